// Round 1
// baseline (287.113 us; speedup 1.0000x reference)
//
#include <hip/hip_runtime.h>
#include <hip/hip_bf16.h>

// SAGEMeanConv: out = relu((segment_sum(h_self[src], dst) + h_self) / (deg+1))
// h_self = feat @ W via bf16 MFMA. Round 9:
//  - GEMM path restructured: A (feat, f32) now staged asynchronously via
//    global_load_lds into a double-buffered 2x32KB LDS tile (chunk k=32),
//    XOR-swizzled through the global source address (rule: linear LDS dest +
//    inverse-swizzled source + swizzled ds_read). B (Wt, 64KB, shared by all
//    blocks -> L2-resident) moved OUT of LDS to direct global 16B loads.
//    This hides the A-load latency that had the whole kernel stalled
//    (MfmaUtil 3%, VALUBusy 4%, HBM 18%: latency-bound).
//  - Scatter path, sort, scans unchanged.

#define IN_FEATS 256
#define OUT_FEATS 128
#define NUM_NODES 100000
#define NUM_EDGES 1600000

#define NB 782            // buckets of 128 nodes
#define EC 128            // edge chunks
#define CHUNK_E 12500     // edges per chunk
#define BCAP 3072         // max edges/bucket
#define GEMM_BLOCKS 391   // ceil(100000/256), 256 rows per block

typedef __attribute__((ext_vector_type(8))) short short8;
typedef __attribute__((ext_vector_type(8))) unsigned short ushort8;
typedef __attribute__((ext_vector_type(4))) float f32x4;

static __device__ inline unsigned short f2bfu(float x) {
    union { __hip_bfloat16 h; unsigned short u; } c;
    c.h = __float2bfloat16(x);
    return c.u;
}
static __device__ inline ushort2 f2bfu2(float x, float y) {
    union { __hip_bfloat162 h; ushort2 u; } c;
    c.h = __float22bfloat162_rn(make_float2(x, y));
    return c.u;
}
static __device__ inline float bf2f(unsigned short h) {
    return __uint_as_float((unsigned)h << 16);
}

// ---------------- K1: convert_wt (blocks 0..127) U passA hist (blocks 128..255) ----------------
__global__ __launch_bounds__(256) void convert_hist(
    const float* __restrict__ W, unsigned short* __restrict__ Wt,
    const int* __restrict__ dst, int* __restrict__ counts)
{
    int b = blockIdx.x;
    int t = threadIdx.x;
    if (b < 128) {
        int i = b * 256 + t;             // 32768 = 128n x 256k
        int n = i >> 8;
        int k = i & 255;
        Wt[i] = f2bfu(W[(size_t)k * OUT_FEATS + n]);
        return;
    }
    int c = b - 128;                     // chunk 0..127
    __shared__ int hist[NB];
    for (int i = t; i < NB; i += 256) hist[i] = 0;
    __syncthreads();
    const int4* dp = (const int4*)(dst + c * CHUNK_E);
    for (int i = t; i < CHUNK_E / 4; i += 256) {
        int4 d4 = dp[i];
        atomicAdd(&hist[d4.x >> 7], 1);
        atomicAdd(&hist[d4.y >> 7], 1);
        atomicAdd(&hist[d4.z >> 7], 1);
        atomicAdd(&hist[d4.w >> 7], 1);
    }
    __syncthreads();
    for (int i = t; i < NB; i += 256) counts[c * NB + i] = hist[i];
}

// ---------------- K2: per-bucket exclusive scan over chunks (in place) ----------------
__global__ __launch_bounds__(128) void scan_chunks(
    int* __restrict__ counts, int* __restrict__ bucket_total)
{
    __shared__ int sd[128];
    int b = blockIdx.x, t = threadIdx.x;
    int v = counts[t * NB + b];
    sd[t] = v;
    __syncthreads();
    for (int o = 1; o < 128; o <<= 1) {
        int x = (t >= o) ? sd[t - o] : 0;
        __syncthreads();
        sd[t] += x;
        __syncthreads();
    }
    counts[t * NB + b] = sd[t] - v;
    if (t == 127) bucket_total[b] = sd[127];
}

// ---------------- K3: exclusive scan of 782 bucket totals ----------------
__global__ __launch_bounds__(256) void scan_buckets(
    const int* __restrict__ bucket_total, int* __restrict__ bucket_base)
{
    __shared__ int sd[256];
    int t = threadIdx.x;
    int base = t * 4;
    int v0 = 0, v1 = 0, v2 = 0, v3 = 0;
    if (base + 3 < NB) {
        int4 v = *(const int4*)&bucket_total[base];
        v0 = v.x; v1 = v.y; v2 = v.z; v3 = v.w;
    } else {
        if (base + 0 < NB) v0 = bucket_total[base + 0];
        if (base + 1 < NB) v1 = bucket_total[base + 1];
        if (base + 2 < NB) v2 = bucket_total[base + 2];
        if (base + 3 < NB) v3 = bucket_total[base + 3];
    }
    int s = v0 + v1 + v2 + v3;
    sd[t] = s;
    __syncthreads();
    for (int o = 1; o < 256; o <<= 1) {
        int x = (t >= o) ? sd[t - o] : 0;
        __syncthreads();
        sd[t] += x;
        __syncthreads();
    }
    int e0 = sd[t] - s, e1 = e0 + v0, e2 = e1 + v1, e3 = e2 + v2;
    if (base + 0 < NB) bucket_base[base + 0] = e0;
    if (base + 1 < NB) bucket_base[base + 1] = e1;
    if (base + 2 < NB) bucket_base[base + 2] = e2;
    if (base + 3 < NB) bucket_base[base + 3] = e3;
}

// Stage one k-chunk of A ([256 rows][32 k] f32 = 32KB) into LDS buffer `buf`
// via async global_load_lds. LDS dest is LINEAR (wave-uniform base + lane*16);
// the XOR swizzle (granule g ^= r&7) is applied on the GLOBAL source address,
// and undone on the ds_read side. Source row clamped to M-1 (garbage rows
// are computed but never stored).
static __device__ inline void stage_chunk(
    const float* __restrict__ feat, char* smem, int buf,
    int bm0, int k0, int t, int M)
{
#pragma unroll
    for (int j = 0; j < 4; ++j) {
        int G = j * 512 + t;             // granule 0..2047 (16B each)
        int r = G >> 3;                  // local row 0..255
        int g = G & 7;                   // granule within row
        int srow = bm0 + r;
        if (srow > M - 1) srow = M - 1;
        const float* src = feat + (size_t)srow * IN_FEATS + k0 + ((g ^ (r & 7)) << 2);
        __builtin_amdgcn_global_load_lds(
            (const __attribute__((address_space(1))) unsigned int*)src,
            (__attribute__((address_space(3))) unsigned int*)(smem + buf * 32768 + G * 16),
            16, 0, 0);
    }
}

// ---------------- K4: gemm (blocks 0..390) U chunk-scatter (391..518), 512 thr ----------------
__global__ __launch_bounds__(512, 4) void gemm_scatter(
    const float* __restrict__ feat, const unsigned short* __restrict__ Wt,
    unsigned short* __restrict__ hself16, int M,
    const int* __restrict__ src, const int* __restrict__ dst,
    const int* __restrict__ counts, const int* __restrict__ bucket_base,
    int* __restrict__ bedges)
{
    __shared__ char smem_raw[65536];
    const int tid = threadIdx.x;

    if (blockIdx.x >= GEMM_BLOCKS) {
        // ---------------- scatter path ----------------
        int c = blockIdx.x - GEMM_BLOCKS;          // chunk 0..127
        int* cur = (int*)smem_raw;
        for (int i = tid; i < NB; i += 512)
            cur[i] = bucket_base[i] + counts[c * NB + i];
        __syncthreads();
        const int4* dp = (const int4*)(dst + c * CHUNK_E);
        const int4* sp = (const int4*)(src + c * CHUNK_E);
        for (int i = tid; i < CHUNK_E / 4; i += 512) {
            int4 d4 = dp[i];
            int4 s4 = sp[i];
            int dv[4] = { d4.x, d4.y, d4.z, d4.w };
            int sv[4] = { s4.x, s4.y, s4.z, s4.w };
#pragma unroll
            for (int j = 0; j < 4; ++j) {
                int d = dv[j];
                int slot = atomicAdd(&cur[d >> 7], 1);
                bedges[slot] = sv[j] | ((d & 127) << 17);
            }
        }
        return;
    }

    // ---------------- gemm path ----------------
    const int w  = tid >> 6;                 // wave 0..7, owns rows w*32..+31
    const int l  = tid & 63;
    const int lf = l & 15;
    const int lg = (l >> 4) & 3;
    const int bm0 = blockIdx.x * 256;

    f32x4 acc[2][8];
#pragma unroll
    for (int mt = 0; mt < 2; ++mt)
#pragma unroll
        for (int nt = 0; nt < 8; ++nt)
            acc[mt][nt] = (f32x4){0.f, 0.f, 0.f, 0.f};

    // prologue: stage chunk 0
    stage_chunk(feat, smem_raw, 0, bm0, 0, tid, M);
    __syncthreads();                         // vmcnt(0) drain -> chunk 0 resident

#pragma unroll
    for (int kc = 0; kc < 8; ++kc) {
        const int buf = kc & 1;
        // issue next chunk's async staging first (overlaps with compute below)
        if (kc < 7)
            stage_chunk(feat, smem_raw, buf ^ 1, bm0, (kc + 1) * 32, tid, M);

        const int k8 = kc * 4;               // k-granule base (8 elems each)

        // A fragments from LDS (f32, swizzled), inline cvt to bf16
        short8 af[2];
#pragma unroll
        for (int mt = 0; mt < 2; ++mt) {
            int r  = w * 32 + mt * 16 + lf;
            int rs = r & 7;
            const char* base = smem_raw + buf * 32768 + r * 128;
            float4 f0 = *(const float4*)(base + ((((lg << 1) + 0) ^ rs) << 4));
            float4 f1 = *(const float4*)(base + ((((lg << 1) + 1) ^ rs) << 4));
            ushort2 c0 = f2bfu2(f0.x, f0.y);
            ushort2 c1 = f2bfu2(f0.z, f0.w);
            ushort2 c2 = f2bfu2(f1.x, f1.y);
            ushort2 c3 = f2bfu2(f1.z, f1.w);
            af[mt] = (short8){ (short)c0.x, (short)c0.y, (short)c1.x, (short)c1.y,
                               (short)c2.x, (short)c2.y, (short)c3.x, (short)c3.y };
        }

        // B fragments direct from global Wt (64KB, shared by all blocks -> L2-hot);
        // 2 n-halves to bound registers
#pragma unroll
        for (int nh = 0; nh < 2; ++nh) {
            short8 bf[4];
#pragma unroll
            for (int q = 0; q < 4; ++q) {
                int nt = nh * 4 + q;
                int n = nt * 16 + lf;
                bf[q] = *(const short8*)(Wt + (size_t)n * IN_FEATS + (k8 + lg) * 8);
            }
#pragma unroll
            for (int q = 0; q < 4; ++q) {
                int nt = nh * 4 + q;
                acc[0][nt] = __builtin_amdgcn_mfma_f32_16x16x32_bf16(af[0], bf[q], acc[0][nt], 0, 0, 0);
                acc[1][nt] = __builtin_amdgcn_mfma_f32_16x16x32_bf16(af[1], bf[q], acc[1][nt], 0, 0, 0);
            }
        }

        // barrier: (a) drains vmcnt -> staged chunk resident for next iter,
        // (b) all waves done reading buf before iter kc+1 overwrites buf^1's pair
        __syncthreads();
    }

    // ---- epilogue: reuse LDS (A buffers dead) for row-major transpose, coalesced stores ----
    unsigned short* ep = (unsigned short*)smem_raw;   // [256 rows][128 cols]
#pragma unroll
    for (int mt = 0; mt < 2; ++mt)
#pragma unroll
        for (int nt = 0; nt < 8; ++nt)
#pragma unroll
            for (int r = 0; r < 4; ++r) {
                int row = w * 32 + mt * 16 + lg * 4 + r;
                ep[row * 128 + nt * 16 + lf] = f2bfu(acc[mt][nt][r]);
            }
    __syncthreads();
#pragma unroll
    for (int i = 0; i < 8; ++i) {
        int lrow = w * 32 + i * 4 + (l >> 4);
        ushort8 v = *(const ushort8*)(ep + lrow * 128 + (l & 15) * 8);
        int grow = bm0 + lrow;
        if (grow < M)
            *(ushort8*)(hself16 + (size_t)grow * OUT_FEATS + (l & 15) * 8) = v;
    }
}

// ---------------- K5: per-bucket LDS counting sort + fused gather/finalize ----------------
// 512 threads / 8 waves per block: NB=782 blocks was grid-capping occupancy.
__global__ __launch_bounds__(512, 8) void sort_gather(
    const int* __restrict__ bucket_base, const int* __restrict__ bucket_total,
    const int* __restrict__ bedges, const unsigned short* __restrict__ hself16,
    float* __restrict__ out)
{
    __shared__ int sorted[BCAP];
    __shared__ int cnt[128], off[128], cursor[128], sd[128];

    int b = blockIdx.x, t = threadIdx.x;
    int base = bucket_base[b];
    int tot = bucket_total[b];
    if (tot > BCAP) tot = BCAP;
    int nnodes = NUM_NODES - b * 128;
    if (nnodes > 128) nnodes = 128;

    if (t < 128) cnt[t] = 0;
    __syncthreads();
    for (int i = t; i < tot; i += 512)
        atomicAdd(&cnt[bedges[base + i] >> 17], 1);
    __syncthreads();
    if (t < 128) sd[t] = cnt[t];
    __syncthreads();
    for (int o = 1; o < 128; o <<= 1) {
        int x = 0;
        if (t < 128 && t >= o) x = sd[t - o];
        __syncthreads();
        if (t < 128) sd[t] += x;
        __syncthreads();
    }
    if (t < 128) { int e = sd[t] - cnt[t]; off[t] = e; cursor[t] = e; }
    __syncthreads();
    for (int i = t; i < tot; i += 512) {
        int e = bedges[base + i];           // re-read (L2-hot)
        int r = atomicAdd(&cursor[e >> 17], 1);
        sorted[r] = e & 0x1FFFF;
    }
    __syncthreads();

    // gather: 8 waves; wave w handles local nodes w, w+8, ...; 16 edges in flight
    int w = t >> 6, l = t & 63, lg = l >> 4, lf = l & 15;
    for (int ln = w; ln < nnodes; ln += 8) {
        int beg = off[ln];
        int end = beg + cnt[ln];
        float acc[8];
#pragma unroll
        for (int i = 0; i < 8; ++i) acc[i] = 0.f;
        for (int j0 = beg; j0 < end; j0 += 16) {
            int  jj[4];
            bool pp[4];
            int  ss[4];
#pragma unroll
            for (int q = 0; q < 4; ++q) {
                jj[q] = j0 + q * 4 + lg;
                pp[q] = jj[q] < end;
                ss[q] = pp[q] ? sorted[jj[q]] : 0;
            }
            ushort8 h[4];
#pragma unroll
            for (int q = 0; q < 4; ++q)
                h[q] = *(const ushort8*)(hself16 + (size_t)ss[q] * OUT_FEATS + lf * 8);
#pragma unroll
            for (int q = 0; q < 4; ++q)
                if (pp[q]) {
#pragma unroll
                    for (int i = 0; i < 8; ++i) acc[i] += bf2f(h[q][i]);
                }
        }
#pragma unroll
        for (int i = 0; i < 8; ++i) {
            acc[i] += __shfl_xor(acc[i], 16, 64);
            acc[i] += __shfl_xor(acc[i], 32, 64);
        }
        if (lg == 0) {
            int n = b * 128 + ln;
            float inv = 1.0f / (float)(end - beg + 1);
            ushort8 hs = *(const ushort8*)(hself16 + (size_t)n * OUT_FEATS + lf * 8);
            float v[8];
#pragma unroll
            for (int i = 0; i < 8; ++i)
                v[i] = fmaxf((acc[i] + bf2f(hs[i])) * inv, 0.f);
            float4* op = (float4*)(out + (size_t)n * OUT_FEATS + lf * 8);
            op[0] = make_float4(v[0], v[1], v[2], v[3]);
            op[1] = make_float4(v[4], v[5], v[6], v[7]);
        }
    }
}

extern "C" void kernel_launch(void* const* d_in, const int* in_sizes, int n_in,
                              void* d_out, int out_size, void* d_ws, size_t ws_size,
                              hipStream_t stream) {
    const float* feat = (const float*)d_in[0];
    const float* W    = (const float*)d_in[1];
    const int*   src  = (const int*)d_in[2];
    const int*   dst  = (const int*)d_in[3];
    float* out = (float*)d_out;

    char* ws = (char*)d_ws;
    unsigned short* hself16 = (unsigned short*)ws;                 // 25,600,000 B
    unsigned short* Wt      = (unsigned short*)(ws + 25600000);    //     65,536 B
    int* counts       = (int*)(ws + 25665536);                     //    400,384 B
    int* bucket_total = (int*)(ws + 26065920);                     //      3,200 B
    int* bucket_base  = (int*)(ws + 26069120);                     //      3,200 B
    int* bedges       = (int*)(ws + 26072320);                     //  6,400,000 B

    convert_hist<<<256, 256, 0, stream>>>(W, Wt, dst, counts);
    scan_chunks<<<NB, 128, 0, stream>>>(counts, bucket_total);
    scan_buckets<<<1, 256, 0, stream>>>(bucket_total, bucket_base);
    gemm_scatter<<<GEMM_BLOCKS + EC, 512, 0, stream>>>(
        feat, Wt, hself16, NUM_NODES, src, dst, counts, bucket_base, bedges);
    sort_gather<<<NB, 512, 0, stream>>>(bucket_base, bucket_total, bedges, hself16, out);
}